// Round 11
// baseline (278.214 us; speedup 1.0000x reference)
//
#include <hip/hip_runtime.h>
#include <hip/hip_bf16.h>

#define N_NODES 50000
#define N_EDGES 600000
#define DIM 128
#define EPS 1e-5f

#define NPB 64                                   // nodes per gemm tile
#define GEMM_GRID ((N_NODES + NPB - 1) / NPB)    // 782
#define HIST_BLOCKS 512
#define NSLICE 8                                 // channel slices -> XCDs
#define SCAN_NB 49                               // ceil(50000/1024)
#define SORT_NB 49
#define CURSOR_INT4 ((N_NODES + 256) / 4)        // counts+flags+dhist+dcur+dbase
#define PREP_ZB ((CURSOR_INT4 + 255) / 256)      // 50 zero blocks
#define NWG ((N_NODES + 31) / 32)                // 1563 wave-groups (32 nodes each)
#define GATHER_GRID (((NWG + 3) / 4) * 8)        // 391*8 = 3128

typedef float  f32x4   __attribute__((ext_vector_type(4)));
typedef short  s16x8   __attribute__((ext_vector_type(8)));
typedef unsigned short u16x4 __attribute__((ext_vector_type(4)));

__device__ __forceinline__ unsigned short f2b(float f) {   // f32 -> bf16 RNE
    unsigned int u = __float_as_uint(f);
    return (unsigned short)((u + 0x7fffu + ((u >> 16) & 1u)) >> 16);
}
__device__ __forceinline__ float b2f(unsigned short h) {
    return __uint_as_float(((unsigned int)h) << 16);
}

// ---- W fragment pre-pack (+ zero of cursor/flags/dhist/dcur/dbase) ----
// wb[cc(8)][ks(4)][lane(64)][j(8)] bf16 hi/lo:
//   k = ks*32 + (lane>>4)*8 + j, c = cc*16 + (lane&15), value = W[(k+1)*DIM + c]
__global__ __launch_bounds__(256) void prep_kernel(
    const float* __restrict__ W1, const float* __restrict__ W2,
    short* __restrict__ wb1h, short* __restrict__ wb1l,
    short* __restrict__ wb2h, short* __restrict__ wb2l,
    int* __restrict__ cursor)
{
    if (blockIdx.x >= 16) {                      // zero counts + flags + sort arrays
        int idx4 = (blockIdx.x - 16) * 256 + threadIdx.x;
        if (idx4 < CURSOR_INT4)
            ((int4*)cursor)[idx4] = make_int4(0, 0, 0, 0);
        return;
    }
    const int layer = blockIdx.x >> 3;
    const int fid = (blockIdx.x & 7) * 256 + threadIdx.x;   // 0..2047
    const int lane = fid & 63;
    const int ck = fid >> 6;                                // cc*4+ks
    const int k0 = (ck & 3) * 32 + (lane >> 4) * 8;
    const int c  = (ck >> 2) * 16 + (lane & 15);
    const float* Wsrc = layer ? W2 : W1;
    short* dh = layer ? wb2h : wb1h;
    short* dl = layer ? wb2l : wb1l;
    s16x8 h, l;
#pragma unroll
    for (int j = 0; j < 8; ++j) {
        float v = Wsrc[(k0 + j + 1) * DIM + c];
        unsigned short hh = f2b(v);
        h[j] = (short)hh;
        l[j] = (short)f2b(v - b2f(hh));
    }
    *(s16x8*)(dh + (size_t)fid * 8) = h;
    *(s16x8*)(dl + (size_t)fid * 8) = l;
}

// MFMA GEMM: tile M=64 nodes x N=128 ch, full K=128 staged once.
// B (W) fragments live in registers for the whole block; LDS = x tile only.
// 3-MFMA error compensation: Ah*Bh + Ah*Bl + Al*Bh (~2^-17 input precision).
__device__ __forceinline__ void gemm_body(
    const float* __restrict__ xin,
    const short* __restrict__ wbh, const short* __restrict__ wbl,
    const float* __restrict__ W, const float* __restrict__ bias,
    const float* __restrict__ tptr,
    float* __restrict__ sout, int tile, char* lds)
{
    char* ah = lds;                  // [64 n][128 k] bf16: byte = n*256+k*2 ^ ((n&7)<<4)
    char* al = lds + 16384;

    const int tid  = threadIdx.x;
    const int nb   = tile * NPB;
    const int lane = tid & 63;
    const int wv   = tid >> 6;       // wave -> ch strip [32wv, 32wv+32)
    const int g    = lane >> 4;
    const int c16  = lane & 15;

    // --- B fragments -> registers (16 x 16B coalesced loads per lane) ---
    s16x8 Bh[2][4], Bl[2][4];
#pragma unroll
    for (int n = 0; n < 2; ++n) {
        int cc = wv * 2 + n;
#pragma unroll
        for (int ks = 0; ks < 4; ++ks) {
            size_t fi = (size_t)((cc * 4 + ks) * 64 + lane) * 8;
            Bh[n][ks] = *(const s16x8*)(wbh + fi);
            Bl[n][ks] = *(const s16x8*)(wbl + fi);
        }
    }

    // --- stage x tile (hi/lo bf16), 8 float4 per thread ---
    const float4* xin4 = (const float4*)xin;
#pragma unroll
    for (int i = 0; i < 8; ++i) {
        int f4 = tid + i * 256;      // 0..2047
        int nl = f4 >> 5;            // node 0..63
        int q  = f4 & 31;            // float4 along k
        int node = nb + nl;
        float4 v = make_float4(0.f, 0.f, 0.f, 0.f);
        if (node < N_NODES) v = xin4[(size_t)node * 32 + q];
        unsigned short h0 = f2b(v.x), h1 = f2b(v.y), h2 = f2b(v.z), h3 = f2b(v.w);
        unsigned short l0 = f2b(v.x - b2f(h0)), l1 = f2b(v.y - b2f(h1));
        unsigned short l2 = f2b(v.z - b2f(h2)), l3 = f2b(v.w - b2f(h3));
        int byt = (nl * 256 + q * 8) ^ ((nl & 7) << 4);
        *(u16x4*)(ah + byt) = (u16x4){h0, h1, h2, h3};
        *(u16x4*)(al + byt) = (u16x4){l0, l1, l2, l3};
    }
    __syncthreads();

    f32x4 acc[4][2];
#pragma unroll
    for (int m = 0; m < 4; ++m)
#pragma unroll
        for (int n = 0; n < 2; ++n)
            acc[m][n] = (f32x4){0.f, 0.f, 0.f, 0.f};

#pragma unroll
    for (int ks = 0; ks < 4; ++ks) {
        s16x8 Ah[4];
#pragma unroll
        for (int m = 0; m < 4; ++m) {
            int node = m * 16 + c16;
            int byt = (node * 256 + ks * 64 + g * 16) ^ ((node & 7) << 4);
            Ah[m] = *(const s16x8*)(ah + byt);
        }
#pragma unroll
        for (int m = 0; m < 4; ++m)
#pragma unroll
            for (int n = 0; n < 2; ++n) {
                acc[m][n] = __builtin_amdgcn_mfma_f32_16x16x32_bf16(Ah[m], Bh[n][ks], acc[m][n], 0, 0, 0);
                acc[m][n] = __builtin_amdgcn_mfma_f32_16x16x32_bf16(Ah[m], Bl[n][ks], acc[m][n], 0, 0, 0);
            }
        s16x8 Alo[4];
#pragma unroll
        for (int m = 0; m < 4; ++m) {
            int node = m * 16 + c16;
            int byt = (node * 256 + ks * 64 + g * 16) ^ ((node & 7) << 4);
            Alo[m] = *(const s16x8*)(al + byt);
        }
#pragma unroll
        for (int m = 0; m < 4; ++m)
#pragma unroll
            for (int n = 0; n < 2; ++n)
                acc[m][n] = __builtin_amdgcn_mfma_f32_16x16x32_bf16(Alo[m], Bh[n][ks], acc[m][n], 0, 0, 0);
    }

    // --- epilogue: + t*W[0][c] + bias[c]; D row=(g*4+r), col=c16 (m89) ---
    const float tval = *tptr;
    float w0[2], bb[2];
#pragma unroll
    for (int n = 0; n < 2; ++n) {
        int c = wv * 32 + n * 16 + c16;
        w0[n] = W[c];
        bb[n] = bias[c];
    }
#pragma unroll
    for (int m = 0; m < 4; ++m) {
        int node0 = nb + m * 16 + g * 4;
#pragma unroll
        for (int n = 0; n < 2; ++n) {
            size_t sbase = (size_t)(wv * 2 + n) * N_NODES * 16 + c16;
#pragma unroll
            for (int r = 0; r < 4; ++r) {
                int nd = node0 + r;
                if (nd < N_NODES)
                    sout[sbase + (size_t)nd * 16] = acc[m][n][r] + tval * w0[n] + bb[n];
            }
        }
    }
}

// gemm layer-1 + histogram (independent work, merged dispatch)
__global__ __launch_bounds__(256) void gemm_hist_kernel(
    const float* __restrict__ xin,
    const short* __restrict__ wbh, const short* __restrict__ wbl,
    const float* __restrict__ W, const float* __restrict__ bias,
    const float* __restrict__ tptr, float* __restrict__ sout,
    const int* __restrict__ tgt, int* __restrict__ cursor)
{
    __shared__ __align__(16) char lds[32768];   // 32 KB (hist blocks leave it unused)
    if (blockIdx.x < GEMM_GRID) {
        gemm_body(xin, wbh, wbl, W, bias, tptr, sout, blockIdx.x, lds);
    } else {
        int e = (blockIdx.x - GEMM_GRID) * 256 + threadIdx.x;
        for (; e < N_EDGES; e += HIST_BLOCKS * 256)
            atomicAdd(&cursor[tgt[e]], 1);
    }
}

__global__ __launch_bounds__(256) void gemm_kernel(
    const float* __restrict__ xin,
    const short* __restrict__ wbh, const short* __restrict__ wbl,
    const float* __restrict__ W, const float* __restrict__ bias,
    const float* __restrict__ tptr, float* __restrict__ sout)
{
    __shared__ __align__(16) char lds[32768];
    gemm_body(xin, wbh, wbl, W, bias, tptr, sout, blockIdx.x, lds);
}

// merged scan (blocks 0..48) + degree counting-sort (blocks 49..97).
// Both read only the post-hist counts; disjoint flag sets; 98 co-resident blocks.
// scan: flags[0]=ticket, flags[1]=bsum2-ready. sort: flags[2]=ticket, flags[3]=dbase-ready.
__global__ __launch_bounds__(256) void scan_sort_kernel(
    const int* __restrict__ counts, int* __restrict__ bsum,
    int* __restrict__ bsum2, int* __restrict__ flags,
    int* __restrict__ rowptr,
    int* __restrict__ dhist, int* __restrict__ dcur,
    int* __restrict__ dbase, int* __restrict__ perm)
{
    __shared__ int sh[256];
    __shared__ int lh[64];
    __shared__ int gb[64];
    __shared__ int lbase[64];
    __shared__ int amILast;
    __shared__ int sbase;
    const int tid = threadIdx.x;
    const int n4 = N_NODES / 4;                  // 12500

    if (blockIdx.x < SCAN_NB) {
        const int b = blockIdx.x;
        int idx4 = b * 256 + tid;
        int4 c = make_int4(0, 0, 0, 0);
        if (idx4 < n4) c = ((const int4*)counts)[idx4];
        int tsum = c.x + c.y + c.z + c.w;

        sh[tid] = tsum;
        __syncthreads();
#pragma unroll
        for (int off = 1; off < 256; off <<= 1) {
            int v = (tid >= off) ? sh[tid - off] : 0;
            __syncthreads();
            sh[tid] += v;
            __syncthreads();
        }
        int incl = sh[tid];

        if (tid == 0) {
            atomicExch(&bsum[b], sh[255]);       // device-scope publish
            amILast = (atomicAdd(&flags[0], 1) == SCAN_NB - 1);
        }
        __syncthreads();

        if (amILast) {
            if (tid < 64) {                      // one wave scans 49 sums
                int v = (tid < SCAN_NB) ? atomicAdd(&bsum[tid], 0) : 0;
                int incl2 = v;
#pragma unroll
                for (int off = 1; off < 64; off <<= 1) {
                    int u = __shfl_up(incl2, off);
                    if ((threadIdx.x & 63) >= off) incl2 += u;
                }
                if (tid < SCAN_NB) atomicExch(&bsum2[tid], incl2 - v);
            }
            __syncthreads();
            if (tid == 0) atomicExch(&flags[1], 1);
        }

        if (tid == 0) {
            while (atomicAdd(&flags[1], 0) == 0) __builtin_amdgcn_s_sleep(2);
            sbase = atomicAdd(&bsum2[b], 0);
        }
        __syncthreads();

        int base = sbase + incl - tsum;          // exclusive prefix for my int4
        if (idx4 < n4) {
            int4 r;
            r.x = base;
            r.y = base + c.x;
            r.z = r.y + c.y;
            r.w = r.z + c.z;
            ((int4*)rowptr)[idx4] = r;
            if (idx4 == n4 - 1) rowptr[N_NODES] = r.w + c.w;
        }
    } else {
        const int b = blockIdx.x - SCAN_NB;      // sort block 0..48
        int idx4 = b * 256 + tid;
        bool have = idx4 < n4;

        if (tid < 64) lh[tid] = 0;
        __syncthreads();

        int4 c = make_int4(0, 0, 0, 0);
        if (have) c = ((const int4*)counts)[idx4];
        int d0 = min(c.x, 63), d1 = min(c.y, 63), d2 = min(c.z, 63), d3 = min(c.w, 63);
        int o0 = 0, o1 = 0, o2 = 0, o3 = 0;
        if (have) {                              // LDS hist + within-block offsets
            o0 = atomicAdd(&lh[d0], 1);
            o1 = atomicAdd(&lh[d1], 1);
            o2 = atomicAdd(&lh[d2], 1);
            o3 = atomicAdd(&lh[d3], 1);
        }
        __syncthreads();
        if (tid < 64 && lh[tid] > 0) atomicAdd(&dhist[tid], lh[tid]);
        __syncthreads();
        if (tid == 0)
            amILast = (atomicAdd(&flags[2], 1) == SORT_NB - 1);
        __syncthreads();

        if (amILast) {
            if (tid < 64) {                      // exclusive scan of 64 bins
                int v = atomicAdd(&dhist[tid], 0);
                int incl = v;
#pragma unroll
                for (int off = 1; off < 64; off <<= 1) {
                    int u = __shfl_up(incl, off);
                    if ((tid & 63) >= off) incl += u;
                }
                atomicExch(&dbase[tid], incl - v);
            }
            __syncthreads();
            if (tid == 0) atomicExch(&flags[3], 1);
        }

        if (tid == 0) {
            while (atomicAdd(&flags[3], 0) == 0) __builtin_amdgcn_s_sleep(2);
        }
        __syncthreads();

        if (tid < 64) {
            lbase[tid] = atomicAdd(&dbase[tid], 0);
            gb[tid]    = atomicAdd(&dcur[tid], lh[tid]);   // block's range in bin
        }
        __syncthreads();

        if (have) {
            int n0 = idx4 * 4;
            perm[lbase[d0] + gb[d0] + o0] = n0;
            perm[lbase[d1] + gb[d1] + o1] = n0 + 1;
            perm[lbase[d2] + gb[d2] + o2] = n0 + 2;
            perm[lbase[d3] + gb[d3] + o3] = n0 + 3;
        }
    }
}

__global__ __launch_bounds__(256) void place_kernel(
    const int* __restrict__ src, const int* __restrict__ tgt,
    const int* __restrict__ rowptr,
    int* __restrict__ cursor, int* __restrict__ eid, int E)
{
    int e = blockIdx.x * 256 + threadIdx.x;
    if (e >= E) return;
    int t = tgt[e];
    int idx = atomicSub(&cursor[t], 1) - 1;
    eid[rowptr[t] + idx] = src[e];
}

// gather + relu + groupnorm. Degree-sorted pairing: each wave owns TWO
// adjacent sorted 16-node groups (positions p, p+16) with one shared
// wave-uniform round count -> 8 eid + 8 gathers in flight, branchless,
// minimal padding (adjacent sorted degrees nearly equal).
__global__ __launch_bounds__(256) void gather_gn_kernel(
    const float4* __restrict__ s_sliced, const int* __restrict__ rowptr,
    const int* __restrict__ eid, const int* __restrict__ perm,
    const float* __restrict__ gamma, const float* __restrict__ beta,
    float* __restrict__ out)
{
    const int slice = blockIdx.x & 7;            // -> XCD (L2-resident slice)
    const int sblk  = blockIdx.x >> 3;           // 0..390
    const int wave  = threadIdx.x >> 6;
    const int lane  = threadIdx.x & 63;
    const int nslot = lane >> 2;
    const int qin   = lane & 3;

    const float4* stab = s_sliced + (size_t)slice * N_NODES * 4;
    const int gch = slice * 16 + qin * 4;
    const float4 gm = *(const float4*)&gamma[gch];
    const float4 bt = *(const float4*)&beta[gch];

    const int wgid = sblk * 4 + wave;            // 0..1563
    const int pA = wgid * 32 + nslot;
    const int pB = pA + 16;
    const bool vA = pA < N_NODES;
    const bool vB = pB < N_NODES;

    int nodeA = 0, begA = 0, endA = 0;
    int nodeB = 0, begB = 0, endB = 0;
    if (vA) { nodeA = perm[pA]; begA = rowptr[nodeA]; endA = rowptr[nodeA + 1]; }
    if (vB) { nodeB = perm[pB]; begB = rowptr[nodeB]; endB = rowptr[nodeB + 1]; }
    const int degA = endA - begA;
    const int degB = endB - begB;

    int nr = max((degA + 3) >> 2, (degB + 3) >> 2);
#pragma unroll
    for (int off = 4; off < 64; off <<= 1)
        nr = max(nr, __shfl_xor(nr, off));
    nr = __builtin_amdgcn_readfirstlane(nr);

    const int clA = min(begA, N_EDGES - 1);
    const int clB = min(begB, N_EDGES - 1);
    float4 accA = make_float4(0.f, 0.f, 0.f, 0.f);
    float4 accB = make_float4(0.f, 0.f, 0.f, 0.f);

#pragma unroll 2
    for (int r = 0; r < nr; ++r) {
        int ea = begA + r * 4;
        int eb = begB + r * 4;
        int a0 = (ea     < endA) ? ea     : clA;
        int a1 = (ea + 1 < endA) ? ea + 1 : clA;
        int a2 = (ea + 2 < endA) ? ea + 2 : clA;
        int a3 = (ea + 3 < endA) ? ea + 3 : clA;
        int b0 = (eb     < endB) ? eb     : clB;
        int b1 = (eb + 1 < endB) ? eb + 1 : clB;
        int b2 = (eb + 2 < endB) ? eb + 2 : clB;
        int b3 = (eb + 3 < endB) ? eb + 3 : clB;
        int sa0 = eid[a0], sa1 = eid[a1], sa2 = eid[a2], sa3 = eid[a3];
        int sb0 = eid[b0], sb1 = eid[b1], sb2 = eid[b2], sb3 = eid[b3];
        float ma0 = (ea     < endA) ? 1.f : 0.f;
        float ma1 = (ea + 1 < endA) ? 1.f : 0.f;
        float ma2 = (ea + 2 < endA) ? 1.f : 0.f;
        float ma3 = (ea + 3 < endA) ? 1.f : 0.f;
        float mb0 = (eb     < endB) ? 1.f : 0.f;
        float mb1 = (eb + 1 < endB) ? 1.f : 0.f;
        float mb2 = (eb + 2 < endB) ? 1.f : 0.f;
        float mb3 = (eb + 3 < endB) ? 1.f : 0.f;
        float4 va0 = stab[(size_t)sa0 * 4 + qin];
        float4 va1 = stab[(size_t)sa1 * 4 + qin];
        float4 va2 = stab[(size_t)sa2 * 4 + qin];
        float4 va3 = stab[(size_t)sa3 * 4 + qin];
        float4 vb0 = stab[(size_t)sb0 * 4 + qin];
        float4 vb1 = stab[(size_t)sb1 * 4 + qin];
        float4 vb2 = stab[(size_t)sb2 * 4 + qin];
        float4 vb3 = stab[(size_t)sb3 * 4 + qin];
        accA.x = fmaf(ma0, va0.x, fmaf(ma1, va1.x, fmaf(ma2, va2.x, fmaf(ma3, va3.x, accA.x))));
        accA.y = fmaf(ma0, va0.y, fmaf(ma1, va1.y, fmaf(ma2, va2.y, fmaf(ma3, va3.y, accA.y))));
        accA.z = fmaf(ma0, va0.z, fmaf(ma1, va1.z, fmaf(ma2, va2.z, fmaf(ma3, va3.z, accA.z))));
        accA.w = fmaf(ma0, va0.w, fmaf(ma1, va1.w, fmaf(ma2, va2.w, fmaf(ma3, va3.w, accA.w))));
        accB.x = fmaf(mb0, vb0.x, fmaf(mb1, vb1.x, fmaf(mb2, vb2.x, fmaf(mb3, vb3.x, accB.x))));
        accB.y = fmaf(mb0, vb0.y, fmaf(mb1, vb1.y, fmaf(mb2, vb2.y, fmaf(mb3, vb3.y, accB.y))));
        accB.z = fmaf(mb0, vb0.z, fmaf(mb1, vb1.z, fmaf(mb2, vb2.z, fmaf(mb3, vb3.z, accB.z))));
        accB.w = fmaf(mb0, vb0.w, fmaf(mb1, vb1.w, fmaf(mb2, vb2.w, fmaf(mb3, vb3.w, accB.w))));
    }

    if (vA) {
        float inv = (degA > 0) ? (1.0f / (float)degA) : 0.0f;
        float ax = fmaxf(accA.x * inv, 0.f);
        float ay = fmaxf(accA.y * inv, 0.f);
        float az = fmaxf(accA.z * inv, 0.f);
        float aw = fmaxf(accA.w * inv, 0.f);
        float mu = 0.25f * (ax + ay + az + aw);
        float dx = ax - mu, dy = ay - mu, dz = az - mu, dw = aw - mu;
        float var = 0.25f * (dx * dx + dy * dy + dz * dz + dw * dw);
        float rs = rsqrtf(var + EPS);
        float4 r;
        r.x = dx * rs * gm.x + bt.x;
        r.y = dy * rs * gm.y + bt.y;
        r.z = dz * rs * gm.z + bt.z;
        r.w = dw * rs * gm.w + bt.w;
        *(float4*)&out[(size_t)nodeA * DIM + gch] = r;
    }
    if (vB) {
        float inv = (degB > 0) ? (1.0f / (float)degB) : 0.0f;
        float ax = fmaxf(accB.x * inv, 0.f);
        float ay = fmaxf(accB.y * inv, 0.f);
        float az = fmaxf(accB.z * inv, 0.f);
        float aw = fmaxf(accB.w * inv, 0.f);
        float mu = 0.25f * (ax + ay + az + aw);
        float dx = ax - mu, dy = ay - mu, dz = az - mu, dw = aw - mu;
        float var = 0.25f * (dx * dx + dy * dy + dz * dz + dw * dw);
        float rs = rsqrtf(var + EPS);
        float4 r;
        r.x = dx * rs * gm.x + bt.x;
        r.y = dy * rs * gm.y + bt.y;
        r.z = dz * rs * gm.z + bt.z;
        r.w = dw * rs * gm.w + bt.w;
        *(float4*)&out[(size_t)nodeB * DIM + gch] = r;
    }
}

extern "C" void kernel_launch(void* const* d_in, const int* in_sizes, int n_in,
                              void* d_out, int out_size, void* d_ws, size_t ws_size,
                              hipStream_t stream) {
    const float* t      = (const float*)d_in[0];
    const float* x      = (const float*)d_in[1];
    const int*   src    = (const int*)d_in[2];
    const int*   tgt    = (const int*)d_in[3];
    const float* W1     = (const float*)d_in[5];
    const float* b1     = (const float*)d_in[6];
    const float* W2     = (const float*)d_in[7];
    const float* b2     = (const float*)d_in[8];
    const float* gamma1 = (const float*)d_in[9];
    const float* beta1  = (const float*)d_in[10];
    const float* gamma2 = (const float*)d_in[11];
    const float* beta2  = (const float*)d_in[12];
    float* out = (float*)d_out;

    const size_t NODE_BYTES = (size_t)N_NODES * DIM * sizeof(float);  // 25.6 MB
    char* ws = (char*)d_ws;
    size_t off = 0;
    float4* s_sliced = (float4*)(ws + off); off += NODE_BYTES;
    int*    rowptr   = (int*)(ws + off);    off += ((size_t)N_NODES + 4) * 4;
    off = (off + 255) & ~(size_t)255;
    int*    cursor   = (int*)(ws + off);    off += ((size_t)N_NODES + 256) * 4;
    int*    flags    = cursor + N_NODES;    // flags[0..3], zeroed by prep
    int*    dhist    = cursor + N_NODES + 64;
    int*    dcur     = cursor + N_NODES + 128;
    int*    dbase    = cursor + N_NODES + 192;
    off = (off + 255) & ~(size_t)255;
    int*    bsum     = (int*)(ws + off);    off += 64 * 4;
    int*    bsum2    = (int*)(ws + off);    off += 64 * 4;
    off = (off + 255) & ~(size_t)255;
    int*    eid      = (int*)(ws + off);    off += (size_t)N_EDGES * 4;
    off = (off + 255) & ~(size_t)255;
    short*  wb1h     = (short*)(ws + off);  off += 16384 * 2;
    short*  wb1l     = (short*)(ws + off);  off += 16384 * 2;
    short*  wb2h     = (short*)(ws + off);  off += 16384 * 2;
    short*  wb2l     = (short*)(ws + off);  off += 16384 * 2;
    off = (off + 255) & ~(size_t)255;
    int*    perm     = (int*)(ws + off);    off += (size_t)N_NODES * 4;

    const int edge_grid = (N_EDGES + 255) / 256;       // 2344

    // 0) pack W + zero counts/flags/sort arrays (one launch)
    prep_kernel<<<16 + PREP_ZB, 256, 0, stream>>>(W1, W2, wb1h, wb1l, wb2h, wb2l, cursor);
    // 1) gemm layer-1 + histogram (independent, merged)
    gemm_hist_kernel<<<GEMM_GRID + HIST_BLOCKS, 256, 0, stream>>>(
        x, wb1h, wb1l, W1, b1, t, (float*)s_sliced, tgt, cursor);
    // 2) scan + degree-sort (independent, merged; 98 co-resident blocks)
    scan_sort_kernel<<<SCAN_NB + SORT_NB, 256, 0, stream>>>(
        cursor, bsum, bsum2, flags, rowptr, dhist, dcur, dbase, perm);
    // 3) place (full edge-parallel grid; decrements cursor)
    place_kernel<<<edge_grid, 256, 0, stream>>>(src, tgt, rowptr, cursor, eid, N_EDGES);
    // 4) gather+GN layer-1  (h lives in d_out)
    gather_gn_kernel<<<GATHER_GRID, 256, 0, stream>>>(s_sliced, rowptr, eid, perm, gamma1, beta1, out);
    // 5) gemm layer-2
    gemm_kernel<<<GEMM_GRID, 256, 0, stream>>>(out, wb2h, wb2l, W2, b2, t, (float*)s_sliced);
    // 6) gather+GN layer-2
    gather_gn_kernel<<<GATHER_GRID, 256, 0, stream>>>(s_sliced, rowptr, eid, perm, gamma2, beta2, out);
}

// Round 12
// 266.149 us; speedup vs baseline: 1.0453x; 1.0453x over previous
//
#include <hip/hip_runtime.h>
#include <hip/hip_bf16.h>

#define N_NODES 50000
#define N_EDGES 600000
#define DIM 128
#define EPS 1e-5f

#define NPB 64                                   // nodes per gemm tile
#define GEMM_GRID ((N_NODES + NPB - 1) / NPB)    // 782
#define HIST_BLOCKS 512
#define NSLICE 8                                 // channel slices -> XCDs
#define GPB 256                                  // gather blocks per slice
#define SCAN_NB 49                               // ceil(50000/1024)
#define CURSOR_INT4 ((N_NODES + 64) / 4)         // 12516 int4s to zero
#define PREP_ZB ((CURSOR_INT4 + 255) / 256)      // 49 zero blocks

typedef float  f32x4   __attribute__((ext_vector_type(4)));
typedef short  s16x8   __attribute__((ext_vector_type(8)));
typedef unsigned short u16x4 __attribute__((ext_vector_type(4)));

__device__ __forceinline__ unsigned short f2b(float f) {   // f32 -> bf16 RNE
    unsigned int u = __float_as_uint(f);
    return (unsigned short)((u + 0x7fffu + ((u >> 16) & 1u)) >> 16);
}
__device__ __forceinline__ float b2f(unsigned short h) {
    return __uint_as_float(((unsigned int)h) << 16);
}

// ---- W fragment pre-pack (+ cursor zero, merged to save a launch) ----
// wb[cc(8)][ks(4)][lane(64)][j(8)] bf16 hi/lo:
//   k = ks*32 + (lane>>4)*8 + j, c = cc*16 + (lane&15), value = W[(k+1)*DIM + c]
__global__ __launch_bounds__(256) void prep_kernel(
    const float* __restrict__ W1, const float* __restrict__ W2,
    short* __restrict__ wb1h, short* __restrict__ wb1l,
    short* __restrict__ wb2h, short* __restrict__ wb2l,
    int* __restrict__ cursor)
{
    if (blockIdx.x >= 16) {                      // zero cursor + flags
        int idx4 = (blockIdx.x - 16) * 256 + threadIdx.x;
        if (idx4 < CURSOR_INT4)
            ((int4*)cursor)[idx4] = make_int4(0, 0, 0, 0);
        return;
    }
    const int layer = blockIdx.x >> 3;
    const int fid = (blockIdx.x & 7) * 256 + threadIdx.x;   // 0..2047
    const int lane = fid & 63;
    const int ck = fid >> 6;                                // cc*4+ks
    const int k0 = (ck & 3) * 32 + (lane >> 4) * 8;
    const int c  = (ck >> 2) * 16 + (lane & 15);
    const float* Wsrc = layer ? W2 : W1;
    short* dh = layer ? wb2h : wb1h;
    short* dl = layer ? wb2l : wb1l;
    s16x8 h, l;
#pragma unroll
    for (int j = 0; j < 8; ++j) {
        float v = Wsrc[(k0 + j + 1) * DIM + c];
        unsigned short hh = f2b(v);
        h[j] = (short)hh;
        l[j] = (short)f2b(v - b2f(hh));
    }
    *(s16x8*)(dh + (size_t)fid * 8) = h;
    *(s16x8*)(dl + (size_t)fid * 8) = l;
}

// MFMA GEMM: tile M=64 nodes x N=128 ch, full K=128 staged once.
// B (W) fragments live in registers for the whole block; LDS = x tile only.
// 3-MFMA error compensation: Ah*Bh + Ah*Bl + Al*Bh (~2^-17 input precision).
__device__ __forceinline__ void gemm_body(
    const float* __restrict__ xin,
    const short* __restrict__ wbh, const short* __restrict__ wbl,
    const float* __restrict__ W, const float* __restrict__ bias,
    const float* __restrict__ tptr,
    float* __restrict__ sout, int tile, char* lds)
{
    char* ah = lds;                  // [64 n][128 k] bf16: byte = n*256+k*2 ^ ((n&7)<<4)
    char* al = lds + 16384;

    const int tid  = threadIdx.x;
    const int nb   = tile * NPB;
    const int lane = tid & 63;
    const int wv   = tid >> 6;       // wave -> ch strip [32wv, 32wv+32)
    const int g    = lane >> 4;
    const int c16  = lane & 15;

    // --- B fragments -> registers (16 x 16B coalesced loads per lane) ---
    s16x8 Bh[2][4], Bl[2][4];
#pragma unroll
    for (int n = 0; n < 2; ++n) {
        int cc = wv * 2 + n;
#pragma unroll
        for (int ks = 0; ks < 4; ++ks) {
            size_t fi = (size_t)((cc * 4 + ks) * 64 + lane) * 8;
            Bh[n][ks] = *(const s16x8*)(wbh + fi);
            Bl[n][ks] = *(const s16x8*)(wbl + fi);
        }
    }

    // --- stage x tile (hi/lo bf16), 8 float4 per thread ---
    const float4* xin4 = (const float4*)xin;
#pragma unroll
    for (int i = 0; i < 8; ++i) {
        int f4 = tid + i * 256;      // 0..2047
        int nl = f4 >> 5;            // node 0..63
        int q  = f4 & 31;            // float4 along k
        int node = nb + nl;
        float4 v = make_float4(0.f, 0.f, 0.f, 0.f);
        if (node < N_NODES) v = xin4[(size_t)node * 32 + q];
        unsigned short h0 = f2b(v.x), h1 = f2b(v.y), h2 = f2b(v.z), h3 = f2b(v.w);
        unsigned short l0 = f2b(v.x - b2f(h0)), l1 = f2b(v.y - b2f(h1));
        unsigned short l2 = f2b(v.z - b2f(h2)), l3 = f2b(v.w - b2f(h3));
        int byt = (nl * 256 + q * 8) ^ ((nl & 7) << 4);
        *(u16x4*)(ah + byt) = (u16x4){h0, h1, h2, h3};
        *(u16x4*)(al + byt) = (u16x4){l0, l1, l2, l3};
    }
    __syncthreads();

    f32x4 acc[4][2];
#pragma unroll
    for (int m = 0; m < 4; ++m)
#pragma unroll
        for (int n = 0; n < 2; ++n)
            acc[m][n] = (f32x4){0.f, 0.f, 0.f, 0.f};

#pragma unroll
    for (int ks = 0; ks < 4; ++ks) {
        s16x8 Ah[4];
#pragma unroll
        for (int m = 0; m < 4; ++m) {
            int node = m * 16 + c16;
            int byt = (node * 256 + ks * 64 + g * 16) ^ ((node & 7) << 4);
            Ah[m] = *(const s16x8*)(ah + byt);
        }
#pragma unroll
        for (int m = 0; m < 4; ++m)
#pragma unroll
            for (int n = 0; n < 2; ++n) {
                acc[m][n] = __builtin_amdgcn_mfma_f32_16x16x32_bf16(Ah[m], Bh[n][ks], acc[m][n], 0, 0, 0);
                acc[m][n] = __builtin_amdgcn_mfma_f32_16x16x32_bf16(Ah[m], Bl[n][ks], acc[m][n], 0, 0, 0);
            }
        s16x8 Alo[4];
#pragma unroll
        for (int m = 0; m < 4; ++m) {
            int node = m * 16 + c16;
            int byt = (node * 256 + ks * 64 + g * 16) ^ ((node & 7) << 4);
            Alo[m] = *(const s16x8*)(al + byt);
        }
#pragma unroll
        for (int m = 0; m < 4; ++m)
#pragma unroll
            for (int n = 0; n < 2; ++n)
                acc[m][n] = __builtin_amdgcn_mfma_f32_16x16x32_bf16(Alo[m], Bh[n][ks], acc[m][n], 0, 0, 0);
    }

    // --- epilogue: + t*W[0][c] + bias[c]; D row=(g*4+r), col=c16 (m89) ---
    const float tval = *tptr;
    float w0[2], bb[2];
#pragma unroll
    for (int n = 0; n < 2; ++n) {
        int c = wv * 32 + n * 16 + c16;
        w0[n] = W[c];
        bb[n] = bias[c];
    }
#pragma unroll
    for (int m = 0; m < 4; ++m) {
        int node0 = nb + m * 16 + g * 4;
#pragma unroll
        for (int n = 0; n < 2; ++n) {
            size_t sbase = (size_t)(wv * 2 + n) * N_NODES * 16 + c16;
#pragma unroll
            for (int r = 0; r < 4; ++r) {
                int nd = node0 + r;
                if (nd < N_NODES)
                    sout[sbase + (size_t)nd * 16] = acc[m][n][r] + tval * w0[n] + bb[n];
            }
        }
    }
}

// gemm layer-1 + histogram (independent work, merged dispatch)
__global__ __launch_bounds__(256) void gemm_hist_kernel(
    const float* __restrict__ xin,
    const short* __restrict__ wbh, const short* __restrict__ wbl,
    const float* __restrict__ W, const float* __restrict__ bias,
    const float* __restrict__ tptr, float* __restrict__ sout,
    const int* __restrict__ tgt, int* __restrict__ cursor)
{
    __shared__ __align__(16) char lds[32768];   // 32 KB (hist blocks leave it unused)
    if (blockIdx.x < GEMM_GRID) {
        gemm_body(xin, wbh, wbl, W, bias, tptr, sout, blockIdx.x, lds);
    } else {
        int e = (blockIdx.x - GEMM_GRID) * 256 + threadIdx.x;
        for (; e < N_EDGES; e += HIST_BLOCKS * 256)
            atomicAdd(&cursor[tgt[e]], 1);
    }
}

__global__ __launch_bounds__(256) void gemm_kernel(
    const float* __restrict__ xin,
    const short* __restrict__ wbh, const short* __restrict__ wbl,
    const float* __restrict__ W, const float* __restrict__ bias,
    const float* __restrict__ tptr, float* __restrict__ sout)
{
    __shared__ __align__(16) char lds[32768];
    gemm_body(xin, wbh, wbl, W, bias, tptr, sout, blockIdx.x, lds);
}

// merged scan (pass1 + bsum-scan + rowptr write), 49 blocks — all co-resident.
// flags[0]=ticket, flags[1]=bsum2-ready (pre-zeroed by prep)
__global__ __launch_bounds__(256) void scan_kernel(
    const int* __restrict__ counts, int* __restrict__ bsum,
    int* __restrict__ bsum2, int* __restrict__ flags,
    int* __restrict__ rowptr)
{
    __shared__ int sh[256];
    __shared__ int amILast;
    __shared__ int sbase;
    const int tid = threadIdx.x;
    const int b = blockIdx.x;
    const int n4 = N_NODES / 4;                  // 12500

    int idx4 = b * 256 + tid;
    int4 c = make_int4(0, 0, 0, 0);
    if (idx4 < n4) c = ((const int4*)counts)[idx4];
    int tsum = c.x + c.y + c.z + c.w;

    // block-wide inclusive scan
    sh[tid] = tsum;
    __syncthreads();
#pragma unroll
    for (int off = 1; off < 256; off <<= 1) {
        int v = (tid >= off) ? sh[tid - off] : 0;
        __syncthreads();
        sh[tid] += v;
        __syncthreads();
    }
    int incl = sh[tid];

    if (tid == 0) {
        atomicExch(&bsum[b], sh[255]);           // device-scope publish
        amILast = (atomicAdd(&flags[0], 1) == SCAN_NB - 1);
    }
    __syncthreads();

    if (amILast) {
        if (tid < 64) {                          // one wave scans 49 sums
            int v = (tid < SCAN_NB) ? atomicAdd(&bsum[tid], 0) : 0;
            int incl2 = v;
#pragma unroll
            for (int off = 1; off < 64; off <<= 1) {
                int u = __shfl_up(incl2, off);
                if ((threadIdx.x & 63) >= off) incl2 += u;
            }
            if (tid < SCAN_NB) atomicExch(&bsum2[tid], incl2 - v);   // exclusive
        }
        __syncthreads();
        if (tid == 0) atomicExch(&flags[1], 1);
    }

    if (tid == 0) {
        while (atomicAdd(&flags[1], 0) == 0) __builtin_amdgcn_s_sleep(2);
        sbase = atomicAdd(&bsum2[b], 0);
    }
    __syncthreads();

    int base = sbase + incl - tsum;              // exclusive prefix for my int4
    if (idx4 < n4) {
        int4 r;
        r.x = base;
        r.y = base + c.x;
        r.z = r.y + c.y;
        r.w = r.z + c.z;
        ((int4*)rowptr)[idx4] = r;
        if (idx4 == n4 - 1) rowptr[N_NODES] = r.w + c.w;
    }
}

__global__ __launch_bounds__(256) void place_kernel(
    const int* __restrict__ src, const int* __restrict__ tgt,
    const int* __restrict__ rowptr,
    int* __restrict__ cursor, int* __restrict__ eid, int E)
{
    int e = blockIdx.x * 256 + threadIdx.x;
    if (e >= E) return;
    int t = tgt[e];
    int idx = atomicSub(&cursor[t], 1) - 1;
    eid[rowptr[t] + idx] = src[e];
}

// gather + relu + groupnorm (XCD-sliced, node-parallel lanes) — R5-proven form
__global__ __launch_bounds__(256) void gather_gn_kernel(
    const float4* __restrict__ s_sliced, const int* __restrict__ rowptr,
    const int* __restrict__ eid,
    const float* __restrict__ gamma, const float* __restrict__ beta,
    float* __restrict__ out, int N)
{
    const int slice = blockIdx.x & 7;
    const int sblk  = blockIdx.x >> 3;
    const int wave  = threadIdx.x >> 6;
    const int lane  = threadIdx.x & 63;
    const int nslot = lane >> 2;
    const int qin   = lane & 3;

    const float4* stab = s_sliced + (size_t)slice * N_NODES * 4;
    const int gch = slice * 16 + qin * 4;
    const float4 gm = *(const float4*)&gamma[gch];
    const float4 bt = *(const float4*)&beta[gch];

    const int wslot0  = sblk * 4 + wave;
    const int nwslots = GPB * 4;

    for (int base = wslot0 * 16; base < N; base += nwslots * 16) {
        int node = base + nslot;
        bool valid = node < N;
        int beg = 0, end = 0;
        if (valid) {
            beg = rowptr[node];
            end = rowptr[node + 1];
        }

        float4 acc = make_float4(0.f, 0.f, 0.f, 0.f);
        int e = beg;
        for (; e + 3 < end; e += 4) {
            int s0 = eid[e];
            int s1 = eid[e + 1];
            int s2 = eid[e + 2];
            int s3 = eid[e + 3];
            float4 v0 = stab[(size_t)s0 * 4 + qin];
            float4 v1 = stab[(size_t)s1 * 4 + qin];
            float4 v2 = stab[(size_t)s2 * 4 + qin];
            float4 v3 = stab[(size_t)s3 * 4 + qin];
            acc.x += (v0.x + v1.x) + (v2.x + v3.x);
            acc.y += (v0.y + v1.y) + (v2.y + v3.y);
            acc.z += (v0.z + v1.z) + (v2.z + v3.z);
            acc.w += (v0.w + v1.w) + (v2.w + v3.w);
        }
        for (; e < end; ++e) {
            int s = eid[e];
            float4 v = stab[(size_t)s * 4 + qin];
            acc.x += v.x;
            acc.y += v.y;
            acc.z += v.z;
            acc.w += v.w;
        }

        if (valid) {
            int deg = end - beg;
            float inv = (deg > 0) ? (1.0f / (float)deg) : 0.0f;
            float ax = fmaxf(acc.x * inv, 0.f);
            float ay = fmaxf(acc.y * inv, 0.f);
            float az = fmaxf(acc.z * inv, 0.f);
            float aw = fmaxf(acc.w * inv, 0.f);
            float mu = 0.25f * (ax + ay + az + aw);
            float dx = ax - mu, dy = ay - mu, dz = az - mu, dw = aw - mu;
            float var = 0.25f * (dx * dx + dy * dy + dz * dz + dw * dw);
            float rs = rsqrtf(var + EPS);
            float4 r;
            r.x = dx * rs * gm.x + bt.x;
            r.y = dy * rs * gm.y + bt.y;
            r.z = dz * rs * gm.z + bt.z;
            r.w = dw * rs * gm.w + bt.w;
            *(float4*)&out[(size_t)node * DIM + gch] = r;
        }
    }
}

extern "C" void kernel_launch(void* const* d_in, const int* in_sizes, int n_in,
                              void* d_out, int out_size, void* d_ws, size_t ws_size,
                              hipStream_t stream) {
    const float* t      = (const float*)d_in[0];
    const float* x      = (const float*)d_in[1];
    const int*   src    = (const int*)d_in[2];
    const int*   tgt    = (const int*)d_in[3];
    const float* W1     = (const float*)d_in[5];
    const float* b1     = (const float*)d_in[6];
    const float* W2     = (const float*)d_in[7];
    const float* b2     = (const float*)d_in[8];
    const float* gamma1 = (const float*)d_in[9];
    const float* beta1  = (const float*)d_in[10];
    const float* gamma2 = (const float*)d_in[11];
    const float* beta2  = (const float*)d_in[12];
    float* out = (float*)d_out;

    const size_t NODE_BYTES = (size_t)N_NODES * DIM * sizeof(float);  // 25.6 MB
    char* ws = (char*)d_ws;
    size_t off = 0;
    float4* s_sliced = (float4*)(ws + off); off += NODE_BYTES;
    int*    rowptr   = (int*)(ws + off);    off += ((size_t)N_NODES + 4) * 4;
    off = (off + 255) & ~(size_t)255;
    int*    cursor   = (int*)(ws + off);    off += ((size_t)N_NODES + 64) * 4;  // counts + flags
    int*    flags    = cursor + N_NODES;    // flags[0..1], zeroed by prep
    off = (off + 255) & ~(size_t)255;
    int*    bsum     = (int*)(ws + off);    off += 64 * 4;
    int*    bsum2    = (int*)(ws + off);    off += 64 * 4;
    off = (off + 255) & ~(size_t)255;
    int*    eid      = (int*)(ws + off);    off += (size_t)N_EDGES * 4;
    off = (off + 255) & ~(size_t)255;
    short*  wb1h     = (short*)(ws + off);  off += 16384 * 2;
    short*  wb1l     = (short*)(ws + off);  off += 16384 * 2;
    short*  wb2h     = (short*)(ws + off);  off += 16384 * 2;
    short*  wb2l     = (short*)(ws + off);  off += 16384 * 2;

    const int edge_grid   = (N_EDGES + 255) / 256;     // 2344
    const int gather_grid = NSLICE * GPB;              // 2048

    // 0) pack W1/W2 into MFMA-B-fragment layout + zero cursor/flags (one launch)
    prep_kernel<<<16 + PREP_ZB, 256, 0, stream>>>(W1, W2, wb1h, wb1l, wb2h, wb2l, cursor);
    // 1) gemm layer-1 + histogram (independent, merged)
    gemm_hist_kernel<<<GEMM_GRID + HIST_BLOCKS, 256, 0, stream>>>(
        x, wb1h, wb1l, W1, b1, t, (float*)s_sliced, tgt, cursor);
    // 2) scan (pass1 + bsum + rowptr merged; 49 co-resident blocks)
    scan_kernel<<<SCAN_NB, 256, 0, stream>>>(cursor, bsum, bsum2, flags, rowptr);
    // 3) place (full edge-parallel grid)
    place_kernel<<<edge_grid, 256, 0, stream>>>(src, tgt, rowptr, cursor, eid, N_EDGES);
    // 4) gather+GN layer-1  (h lives in d_out)
    gather_gn_kernel<<<gather_grid, 256, 0, stream>>>(s_sliced, rowptr, eid, gamma1, beta1, out, N_NODES);
    // 5) gemm layer-2
    gemm_kernel<<<GEMM_GRID, 256, 0, stream>>>(out, wb2h, wb2l, W2, b2, t, (float*)s_sliced);
    // 6) gather+GN layer-2
    gather_gn_kernel<<<gather_grid, 256, 0, stream>>>(s_sliced, rowptr, eid, gamma2, beta2, out, N_NODES);
}